// Round 16
// baseline (801.232 us; speedup 1.0000x reference)
//
#include <hip/hip_runtime.h>
#include <hip/hip_bf16.h>

// FP8Linear: out = Xq @ Wq^T + bias. Reference quantize (scale=1) == RNE
// conversion to OCP e4m3fn; x stored as e4m3(x); w stored as e4m3(w*2^6)
// with MFMA B-scale 2^-6 (e8m0 0x79) so all |w|>=2^-12 quantize EXACTLY.
// GEMM R16: first config combining BOTH session-validated levers:
//  (1) 4 waves/SIMD TLP (16 waves/CU at the 128-reg budget: acc[2][2]=64
//      AGPR + ~64 arch VGPR), and
//  (2) full-tile dbuf prefetch (DMA issued one full tile ahead; the single
//      per-tile __syncthreads' implicit vmcnt(0) drain is ~free at ~2500cyc
//      issue->drain distance >> 900cyc HBM latency).
// R15 diagnosis: latency-bound, both pipes <50% busy (port 42%, MFMA 34%);
// every prior config had TLP or drain-removal, never both.
// 256x256 tile, BK=128, 1024 threads (4Mx4N waves, 64x64 out each),
// dbuf 2x64KB LDS, mfma_scale_f32_32x32x64_f8f6f4, 128B-row XOR swizzle
// (sw=(r&7)<<4, pre-swizzled DMA source), XCD block swizzle.

typedef int i32x4 __attribute__((ext_vector_type(4)));
typedef int i32x8 __attribute__((ext_vector_type(8)));
typedef float f32x16 __attribute__((ext_vector_type(16)));

#define BM 256
#define BN 256
#define BK 128

// clip to +-448, scale (1 or 64), RNE-encode 8 f32 -> 8 e4m3 bytes.
__global__ __launch_bounds__(256) void quant8(
    const float4* __restrict__ in, int2* __restrict__ out, int n8, float scale) {
    int i = blockIdx.x * blockDim.x + threadIdx.x;
    if (i >= n8) return;
    float4 a = in[i * 2];
    float4 b = in[i * 2 + 1];
    float c0 = fminf(fmaxf(a.x, -448.f), 448.f) * scale;
    float c1 = fminf(fmaxf(a.y, -448.f), 448.f) * scale;
    float c2 = fminf(fmaxf(a.z, -448.f), 448.f) * scale;
    float c3 = fminf(fmaxf(a.w, -448.f), 448.f) * scale;
    float c4 = fminf(fmaxf(b.x, -448.f), 448.f) * scale;
    float c5 = fminf(fmaxf(b.y, -448.f), 448.f) * scale;
    float c6 = fminf(fmaxf(b.z, -448.f), 448.f) * scale;
    float c7 = fminf(fmaxf(b.w, -448.f), 448.f) * scale;
    int lo = __builtin_amdgcn_cvt_pk_fp8_f32(c0, c1, 0, false);
    lo = __builtin_amdgcn_cvt_pk_fp8_f32(c2, c3, lo, true);
    int hi = __builtin_amdgcn_cvt_pk_fp8_f32(c4, c5, 0, false);
    hi = __builtin_amdgcn_cvt_pk_fp8_f32(c6, c7, hi, true);
    out[i] = make_int2(lo, hi);
}

__device__ __forceinline__ void gload_lds16(const void* g, void* l) {
    __builtin_amdgcn_global_load_lds(
        (const __attribute__((address_space(1))) void*)g,
        (__attribute__((address_space(3))) void*)l,
        16, 0, 0);
}

// 128B-row tiles. LDS[r][c] holds G[r][c ^ sw(r)], sw(r) = (r&7)<<4.
// Read one lane's 32-byte k-block (logical cols [c0, c0+32)) of `row`.
__device__ __forceinline__ i32x8 frag32(const unsigned char* base, int row, int c0) {
    const int sw = (row & 7) << 4;
    const unsigned char* p = base + row * 128;
    i32x4 lo = *(const i32x4*)(p + (c0 ^ sw));
    i32x4 hi = *(const i32x4*)(p + ((c0 + 16) ^ sw));
    i32x8 r;
    r[0] = lo[0]; r[1] = lo[1]; r[2] = lo[2]; r[3] = lo[3];
    r[4] = hi[0]; r[5] = hi[1]; r[6] = hi[2]; r[7] = hi[3];
    return r;
}

// A: Xq8 [M][K] e4m3, B: Wq8 [N][K] e4m3 (pre-scaled by 2^6), C: [M][N] f32
__global__ __launch_bounds__(1024, 1) void gemm_fp8(
    const unsigned char* __restrict__ A, const unsigned char* __restrict__ B,
    const float* __restrict__ bias, float* __restrict__ C,
    int M, int N, int K) {
    // buf0: A [0,32K) B [32K,64K); buf1: A [64K,96K) B [96K,128K)
    __shared__ unsigned char lds[131072];

    const int tid = threadIdx.x;
    const int lane = tid & 63;
    const int wave = tid >> 6;   // 0..15
    const int wr = wave >> 2;    // 0..3 -> 64 A-rows each
    const int wc = wave & 3;     // 0..3 -> 64 B-cols each

    // XCD-aware bijective block swizzle (nwg % 8 == 0)
    const int nwg = gridDim.x;
    const int per = nwg >> 3;
    const int bid = blockIdx.x;
    const int wg = (bid & 7) * per + (bid >> 3);
    const int mtiles = M / BM;
    const int bm = wg % mtiles;
    const int bn = wg / mtiles;

    const int arow0 = bm * BM, bcol0 = bn * BN;
    const int NT = K / BK;  // 32

    const int rl = lane & 31;    // fragment row-within-32 (A row / B col)
    const int g2 = lane >> 5;    // k-half selector within 64-byte mfma k-range

    const unsigned char* const Ag = A + (size_t)arow0 * K;
    const unsigned char* const Bg = B + (size_t)bcol0 * K;

    // staging (per 16KB chunk = 128 rows x 128B; 1024 threads x 16B = 16KB):
    // thread t: row-in-chunk = t>>3 (0..127), logical col = (t&7)*16,
    // dst linear (DMA constraint), src pre-swizzled (both-sides rule).
    const int srow = tid >> 3;                       // 0..127
    const int ssrc_col = ((tid & 7) * 16) ^ (((tid >> 3) & 7) << 4);
    const int sdst = tid * 16;

    auto stage = [&](unsigned char* Lp, int kt) {
        // A: 32KB = 2 chunks of 128 rows
#pragma unroll
        for (int c = 0; c < 2; ++c)
            gload_lds16(Ag + (size_t)(c * 128 + srow) * K + kt + ssrc_col,
                        Lp + c * 16384 + sdst);
        // B: 32KB = 2 chunks of 128 rows
#pragma unroll
        for (int c = 0; c < 2; ++c)
            gload_lds16(Bg + (size_t)(c * 128 + srow) * K + kt + ssrc_col,
                        Lp + 32768 + c * 16384 + sdst);
    };

    f32x16 acc[2][2] = {};

    // ---- prologue: tile 0 -> buf0
    stage(lds, 0);
    __syncthreads();  // implicit vmcnt(0): tile 0 landed

    for (int t = 0; t < NT; ++t) {
        const int cur = t & 1;
        const unsigned char* Ab = lds + cur * 65536;
        const unsigned char* Bb = Ab + 32768;
        unsigned char* Anx = lds + (cur ^ 1) * 65536;

        // issue next tile's DMAs first: a full tile of latency cover
        if (t + 1 < NT) stage(Anx, (t + 1) * BK);

#pragma unroll
        for (int ks = 0; ks < 2; ++ks) {
            const int c0 = ks * 64 + g2 * 32;
            i32x8 af0 = frag32(Ab, wr * 64 + rl, c0);
            i32x8 af1 = frag32(Ab, wr * 64 + 32 + rl, c0);
            i32x8 bf0 = frag32(Bb, wc * 64 + rl, c0);
            i32x8 bf1 = frag32(Bb, wc * 64 + 32 + rl, c0);

            acc[0][0] = __builtin_amdgcn_mfma_scale_f32_32x32x64_f8f6f4(
                af0, bf0, acc[0][0], 0, 0, 0, 0x7F7F7F7F, 0, 0x79797979);
            acc[0][1] = __builtin_amdgcn_mfma_scale_f32_32x32x64_f8f6f4(
                af0, bf1, acc[0][1], 0, 0, 0, 0x7F7F7F7F, 0, 0x79797979);
            acc[1][0] = __builtin_amdgcn_mfma_scale_f32_32x32x64_f8f6f4(
                af1, bf0, acc[1][0], 0, 0, 0, 0x7F7F7F7F, 0, 0x79797979);
            acc[1][1] = __builtin_amdgcn_mfma_scale_f32_32x32x64_f8f6f4(
                af1, bf1, acc[1][1], 0, 0, 0, 0x7F7F7F7F, 0, 0x79797979);
        }

        // one sync/tile: drains DMAs issued a full tile ago (landed) and
        // publishes the prefetched buffer; protects the consumed one.
        __syncthreads();
    }

    // epilogue: 32x32 C/D: col = lane&31, row = (reg&3)+8*(reg>>2)+4*(lane>>5)
#pragma unroll
    for (int n = 0; n < 2; ++n) {
        int col = bcol0 + wc * 64 + n * 32 + rl;
        float bv = bias[col];
#pragma unroll
        for (int m = 0; m < 2; ++m) {
            int rowb = arow0 + wr * 64 + m * 32 + g2 * 4;
#pragma unroll
            for (int reg = 0; reg < 16; ++reg) {
                int row = rowb + (reg & 3) + 8 * (reg >> 2);
                C[(size_t)row * N + col] = acc[m][n][reg] + bv;
            }
        }
    }
}

extern "C" void kernel_launch(void* const* d_in, const int* in_sizes, int n_in,
                              void* d_out, int out_size, void* d_ws, size_t ws_size,
                              hipStream_t stream) {
    const float* x = (const float*)d_in[0];     // [M,K]
    const float* w = (const float*)d_in[1];     // [N,K]
    const float* bias = (const float*)d_in[2];  // [N]
    float* out = (float*)d_out;

    const int N = in_sizes[2];                 // 16384
    const int K = in_sizes[1] / N;             // 4096
    const int M = in_sizes[0] / K;             // 8192

    unsigned char* xq = (unsigned char*)d_ws;          // M*K = 33.5 MB
    unsigned char* wq = xq + (size_t)M * K;            // N*K = 67 MB

    int nx8 = M * K / 8;
    int nw8 = N * K / 8;
    quant8<<<(nx8 + 255) / 256, 256, 0, stream>>>(
        (const float4*)x, (int2*)xq, nx8, 1.0f);
    quant8<<<(nw8 + 255) / 256, 256, 0, stream>>>(
        (const float4*)w, (int2*)wq, nw8, 64.0f);

    int nwg = (M / BM) * (N / BN);  // 32*64 = 2048, %8==0
    gemm_fp8<<<nwg, 1024, 0, stream>>>(
        xq, wq, bias, out, M, N, K);
}